// Round 6
// baseline (73.823 us; speedup 1.0000x reference)
//
#include <hip/hip_runtime.h>

// Kuramoto helix network v7: v6 + conflict-free LDS slot swizzle.
// A element (m, j) stored at granule-slot m ^ 2*(jg&1) (jg = j>>3):
//   - step writes: 32 active lanes hit 16 distinct dwords x 2 lanes (free)
//     (v6 was 8-way conflicted: 1.81M SQ_LDS_BANK_CONFLICT)
//   - reads stay contiguous b128 (XOR is lane-constant: slot = lr ^ 2*(lg&1))
//   - zero-row slot sets {8..15}/{4..7} closed under ^2 -> fills unchanged.
// STEP restructured per-t {8 MFMA -> upd -> write} with end-of-step barrier
// (one-time prefill of buf0), s_setprio(1) around the compute cluster.

#define NB 2048
#define NIN 512
#define NOUT 128
#define NOSC 256
#define DTT 0.1f

#define WS_WENC (512*1024)
#define WS_WD   (1024*1024)

typedef _Float16 f16;
typedef _Float16 f16x8 __attribute__((ext_vector_type(8)));
typedef float f32x4 __attribute__((ext_vector_type(4)));

__device__ __forceinline__ float wrapf(float t) {
    return t - 6.28318530717958648f * rintf(t * 0.159154943091895336f);
}

__device__ __forceinline__ void upd1(float aS, float aC, float dtom, float dtcc,
                                     float& th, float& s, float& c) {
    float diff = fmaf(c, aS, -(s * aC));
    float dth  = fmaf(diff, dtcc, dtom);
    th += dth;
    float q  = dth * dth;
    float sd = dth * fmaf(q, -0.166666667f, 1.0f);
    float cd = fmaf(q, fmaf(q, 0.0416666679f, -0.5f), 1.0f);
    float ns = fmaf(s, cd,  c * sd);
    float nc = fmaf(c, cd, -(s * sd));
    s = ns; c = nc;
}

// ---- prep: lay K (f16), W_enc (f16 hi/lo), W_dec (f16) out in frag layout ----
__global__ __launch_bounds__(256) void helix_prep(
    const float* __restrict__ Ks, const float* __restrict__ Wenc,
    const float* __restrict__ Wdec, char* __restrict__ ws)
{
    const int g = blockIdx.x * 256 + threadIdx.x;
    if (g < 32768) {                       // K: [l 4][nt 16][kf 8][ln 64]
        const int ln = g & 63, lg = ln >> 4, lr = ln & 15;
        const int kf = (g >> 6) & 7, nt = (g >> 9) & 15, l = (g >> 13) & 3;
        const float* s = Ks + (((size_t)l * NOSC + nt * 16 + lr) * NOSC + kf * 32 + lg * 8);
        f16x8 o;
        #pragma unroll
        for (int e = 0; e < 8; ++e) o[e] = (f16)s[e];
        *(f16x8*)(ws + (size_t)g * 16) = o;
    } else if (g < 65536) {                // Wenc: [nt 16][kf 16][h 2][ln 64]
        const int q = g - 32768;
        const int ln = q & 63, lg = ln >> 4, lr = ln & 15;
        const int h = (q >> 6) & 1, kf = (q >> 7) & 15, nt = (q >> 11) & 15;
        const float* s = Wenc + ((size_t)(nt * 16 + lr) * NIN + kf * 32 + lg * 8);
        f16x8 o;
        #pragma unroll
        for (int e = 0; e < 8; ++e) {
            float v = s[e];
            f16 hi = (f16)v;
            o[e] = h ? (f16)(v - (float)hi) : hi;
        }
        *(f16x8*)(ws + WS_WENC + (size_t)q * 16) = o;
    } else if (g < 69632) {                // Wdec: [nt 8][kf 8][ln 64]
        const int q = g - 65536;
        const int ln = q & 63, lg = ln >> 4, lr = ln & 15;
        const int kf = (q >> 6) & 7, nt = (q >> 9) & 7;
        const float* s = Wdec + ((size_t)(nt * 16 + lr) * NOSC + kf * 32 + lg * 8);
        f16x8 o;
        #pragma unroll
        for (int e = 0; e < 8; ++e) o[e] = (f16)s[e];
        *(f16x8*)(ws + WS_WD + (size_t)q * 16) = o;
    }
}

__global__ __launch_bounds__(256, 2) void helix7(
    const float* __restrict__ x,
    const float* __restrict__ b_enc,
    const float* __restrict__ omegas,
    const float* __restrict__ Kgl,
    const float* __restrict__ mgl,
    const float* __restrict__ b_dec,
    const char* __restrict__ ws,
    float* __restrict__ out)
{
    // [0,16384): encoder A (16x512 f16) -> dynamics dbuf (2x8KB) -> decoder A
    // [16384,20480): th_lds f32[4][256]
    // [20480,20608): coherence partials [wv 4][r 4][2]
    __shared__ __align__(16) char smem[20736];
    float* th_lds = (float*)(smem + 16384);
    float* coh    = (float*)(smem + 20480);

    const int tid = threadIdx.x;
    const int wv = tid >> 6, ln = tid & 63, lg = ln >> 4, lr = ln & 15;
    const int d  = lr >> 3;            // granule-row parity bit for this lane
    const int row0 = blockIdx.x * 4;

    float* out_y   = out;
    float* out_th  = out + (size_t)NB * NOUT;
    float* out_coh = out + (size_t)NB * (NOUT + NOSC);

    const int4 zz = make_int4(0, 0, 0, 0);

    // ---- P0: x -> encoder-A LDS (hi rows 0-3, lo rows 4-7, zeros 8-15) ----
    {
        const int k0 = ln * 8;
        const float* xp = x + (size_t)(row0 + wv) * NIN + k0;
        float4 v0 = *(const float4*)xp;
        float4 v1 = *(const float4*)(xp + 4);
        float vv[8] = {v0.x, v0.y, v0.z, v0.w, v1.x, v1.y, v1.z, v1.w};
        f16x8 hi, lo;
        #pragma unroll
        for (int e = 0; e < 8; ++e) {
            hi[e] = (f16)vv[e];
            lo[e] = (f16)(vv[e] - (float)hi[e]);
        }
        char* base = smem + (k0 >> 3) * 256;
        *(f16x8*)(base + wv * 16)        = hi;
        *(f16x8*)(base + (wv + 4) * 16)  = lo;
        *(int4*)(base + (wv + 8) * 16)   = zz;
        *(int4*)(base + (wv + 12) * 16)  = zz;
    }
    __syncthreads();

    // ---- P1: encoder MFMA (plain layout, separate from dynamics swizzle) ----
    float th[4][2], sv[4][2], cv[4][2];
    {
        f32x4 accH[4] = {{0,0,0,0},{0,0,0,0},{0,0,0,0},{0,0,0,0}};
        f32x4 accL[4] = {{0,0,0,0},{0,0,0,0},{0,0,0,0},{0,0,0,0}};
        const char* aBase = smem + lg * 256 + lr * 16;
        const char* wE0 = ws + WS_WENC + (size_t)(4 * wv + 0) * 32768 + ln * 16;
        const char* wE1 = wE0 + 32768, *wE2 = wE0 + 65536, *wE3 = wE0 + 98304;
        const char* wE[4] = {wE0, wE1, wE2, wE3};
        #pragma unroll 4
        for (int kf = 0; kf < 16; ++kf) {
            f16x8 a = *(const f16x8*)(aBase + kf * 1024);
            #pragma unroll
            for (int t = 0; t < 4; ++t) {
                f16x8 bh = *(const f16x8*)(wE[t] + kf * 2048);
                f16x8 bl = *(const f16x8*)(wE[t] + kf * 2048 + 1024);
                accH[t] = __builtin_amdgcn_mfma_f32_16x16x32_f16(a, bh, accH[t], 0, 0, 0);
                accL[t] = __builtin_amdgcn_mfma_f32_16x16x32_f16(a, bl, accL[t], 0, 0, 0);
            }
        }
        #pragma unroll
        for (int t = 0; t < 4; ++t) {
            const int ct = 64 * wv + 16 * t + lr;
            const float be = b_enc[ct];
            float tp[4];
            #pragma unroll
            for (int e = 0; e < 4; ++e) {
                float v = accH[t][e] + accL[t][e];
                v += __shfl_xor(v, 16);
                tp[e] = v;
            }
            #pragma unroll
            for (int p = 0; p < 2; ++p) {
                th[t][p] = wrapf(tp[(2 * lg + p) & 3] + be);
                sincosf(th[t][p], &sv[t][p], &cv[t][p]);
            }
        }
    }
    __syncthreads();

    // ---- dynamics addresses (swizzled slots) ----
    int wb[4];
    #pragma unroll
    for (int t = 0; t < 4; ++t)
        wb[t] = (8 * wv + 2 * t + d) * 256 + lg * 64 + (lr & 7) * 2;
    const int pz = d << 5;                              // p-bit XOR in bytes
    const int rb = lg * 256 + (lr ^ ((lg & 1) << 1)) * 16;

    // ---- P2: zero dynamics-A slots 8..15 in both buffers + prefill buf0 ----
    #pragma unroll
    for (int q = 0; q < 2; ++q) {
        const int id = tid + q * 256;
        *(int4*)(smem + (id >> 8) * 8192 + ((id & 255) >> 3) * 256 + (8 + (id & 7)) * 16) = zz;
    }
    if (lg < 2) {
        #pragma unroll
        for (int t = 0; t < 4; ++t) {
            *(f16*)(smem + wb[t] + (pz ^ 0))  = (f16)sv[t][0];
            *(f16*)(smem + wb[t] + (pz ^ 16)) = (f16)cv[t][0];
            *(f16*)(smem + wb[t] + (pz ^ 32)) = (f16)sv[t][1];
            *(f16*)(smem + wb[t] + (pz ^ 48)) = (f16)cv[t][1];
        }
    }
    __syncthreads();

    // ---- dynamics ----
    f16x8 Bf[4][8];
    float dtom[4], dtcc;

    auto STEP = [&](const char* Sb, char* Wb) {
        f16x8 a[8];
        #pragma unroll
        for (int kf = 0; kf < 8; ++kf)
            a[kf] = *(const f16x8*)(Sb + kf * 1024 + rb);
        __builtin_amdgcn_s_setprio(1);
        #pragma unroll
        for (int t = 0; t < 4; ++t) {
            f32x4 acc = {0.f, 0.f, 0.f, 0.f};
            #pragma unroll
            for (int kf = 0; kf < 8; ++kf)
                acc = __builtin_amdgcn_mfma_f32_16x16x32_f16(a[kf], Bf[t][kf], acc, 0, 0, 0);
            upd1(acc[0], acc[1], dtom[t], dtcc, th[t][0], sv[t][0], cv[t][0]);
            upd1(acc[2], acc[3], dtom[t], dtcc, th[t][1], sv[t][1], cv[t][1]);
            if (lg < 2) {
                *(f16*)(Wb + wb[t] + (pz ^ 0))  = (f16)sv[t][0];
                *(f16*)(Wb + wb[t] + (pz ^ 16)) = (f16)cv[t][0];
                *(f16*)(Wb + wb[t] + (pz ^ 32)) = (f16)sv[t][1];
                *(f16*)(Wb + wb[t] + (pz ^ 48)) = (f16)cv[t][1];
            }
        }
        __builtin_amdgcn_s_setprio(0);
        __syncthreads();
    };

    for (int l = 0; l < 4; ++l) {
        #pragma unroll
        for (int t = 0; t < 4; ++t) {
            const char* kb = ws + (size_t)l * 131072 + (size_t)(4 * wv + t) * 8192 + ln * 16;
            #pragma unroll
            for (int kf = 0; kf < 8; ++kf)
                Bf[t][kf] = *(const f16x8*)(kb + kf * 1024);
        }
        dtcc = DTT * Kgl[l] * (1.0f / (float)NOSC) * (mgl[l] * 0.5f);
        #pragma unroll
        for (int t = 0; t < 4; ++t)
            dtom[t] = DTT * omegas[l * NOSC + 64 * wv + 16 * t + lr];

        #pragma unroll 1
        for (int p5 = 0; p5 < 5; ++p5) {
            STEP(smem, smem + 8192);
            STEP(smem + 8192, smem);
        }
    }

    // ---- epilogue ----
    // wrap; stage th (f32 for out, f16 decoder-A rows 0-3, swizzled slots)
    if (lg < 2) {
        #pragma unroll
        for (int t = 0; t < 4; ++t)
            #pragma unroll
            for (int p = 0; p < 2; ++p) {
                const int ct = 64 * wv + 16 * t + lr;
                const int r = 2 * lg + p;
                const float wt = wrapf(th[t][p]);
                th_lds[r * NOSC + ct] = wt;
                *(f16*)(smem + (ct >> 3) * 256 + ((r ^ (d << 1)) * 16) + (lr & 7) * 2) = (f16)wt;
            }
    }
    if (tid < 128)   // zero decoder-A slots 4-7 (8-15 still zero from P2)
        *(int4*)(smem + (tid >> 2) * 256 + (4 + (tid & 3)) * 16) = zz;
    #pragma unroll
    for (int p = 0; p < 2; ++p) {
        float pS = sv[0][p] + sv[1][p] + sv[2][p] + sv[3][p];
        float pC = cv[0][p] + cv[1][p] + cv[2][p] + cv[3][p];
        pS += __shfl_xor(pS, 1); pC += __shfl_xor(pC, 1);
        pS += __shfl_xor(pS, 2); pC += __shfl_xor(pC, 2);
        pS += __shfl_xor(pS, 4); pC += __shfl_xor(pC, 4);
        pS += __shfl_xor(pS, 8); pC += __shfl_xor(pC, 8);
        if (lr == 0 && lg < 2) {
            coh[(wv * 4 + 2 * lg + p) * 2]     = pS;
            coh[(wv * 4 + 2 * lg + p) * 2 + 1] = pC;
        }
    }
    __syncthreads();

    // theta out (coalesced)
    {
        float4 v = *(float4*)(th_lds + tid * 4);
        *(float4*)(out_th + (size_t)row0 * NOSC + tid * 4) = v;
    }
    // coherence
    if (tid < 4) {
        float S = 0.f, C = 0.f;
        #pragma unroll
        for (int w2 = 0; w2 < 4; ++w2) {
            S += coh[(w2 * 4 + tid) * 2];
            C += coh[(w2 * 4 + tid) * 2 + 1];
        }
        S *= (1.0f / (float)NOSC);
        C *= (1.0f / (float)NOSC);
        out_coh[row0 + tid] = sqrtf(S * S + C * C);
    }
    // decoder MFMA: wave wv -> out cols [32wv, 32wv+32)
    {
        f32x4 aD[2] = {{0,0,0,0},{0,0,0,0}};
        #pragma unroll
        for (int kf = 0; kf < 8; ++kf) {
            f16x8 a = *(const f16x8*)(smem + kf * 1024 + rb);
            #pragma unroll
            for (int u = 0; u < 2; ++u) {
                f16x8 bw = *(const f16x8*)(ws + WS_WD + (size_t)(2 * wv + u) * 8192 + kf * 1024 + ln * 16);
                aD[u] = __builtin_amdgcn_mfma_f32_16x16x32_f16(a, bw, aD[u], 0, 0, 0);
            }
        }
        if (lg == 0) {
            #pragma unroll
            for (int u = 0; u < 2; ++u) {
                const int col = (2 * wv + u) * 16 + lr;
                const float bd = b_dec[col];
                #pragma unroll
                for (int e = 0; e < 4; ++e)
                    out_y[(size_t)(row0 + e) * NOUT + col] = aD[u][e] + bd;
            }
        }
    }
}

extern "C" void kernel_launch(void* const* d_in, const int* in_sizes, int n_in,
                              void* d_out, int out_size, void* d_ws, size_t ws_size,
                              hipStream_t stream) {
    const float* x     = (const float*)d_in[0];
    const float* W_enc = (const float*)d_in[1];
    const float* b_enc = (const float*)d_in[2];
    const float* Ks    = (const float*)d_in[3];
    const float* omg   = (const float*)d_in[4];
    const float* Kgl   = (const float*)d_in[5];
    const float* mgl   = (const float*)d_in[6];
    const float* W_dec = (const float*)d_in[7];
    const float* b_dec = (const float*)d_in[8];
    char* ws = (char*)d_ws;

    helix_prep<<<272, 256, 0, stream>>>(Ks, W_enc, W_dec, ws);
    helix7<<<NB / 4, 256, 0, stream>>>(x, b_enc, omg, Kgl, mgl, b_dec, ws, (float*)d_out);
}